// Round 15
// baseline (983.635 us; speedup 1.0000x reference)
//
#include <hip/hip_runtime.h>
#include <hip/hip_bf16.h>
#include <cstdint>
#include <cstddef>

typedef __bf16 bf16_t;
typedef bf16_t bf16x8 __attribute__((ext_vector_type(8)));
typedef float  f32x4  __attribute__((ext_vector_type(4)));

__device__ __forceinline__ void gl_lds16(const void* g, void* l) {
  __builtin_amdgcn_global_load_lds(
      (const __attribute__((address_space(1))) void*)g,
      (__attribute__((address_space(3))) void*)l, 16, 0, 0);
}

#define BAR()  __builtin_amdgcn_s_barrier()

// ---------------------------------------------------------------------------
// prep kernel: fused pack_x0 + 6 weight transposes (fp32 -> bf16, KxN -> Npad x Kpad)
// ---------------------------------------------------------------------------
__device__ __forceinline__ void transpose_tile(
    const float* __restrict__ W, bf16_t* __restrict__ Wt,
    int K, int N, int Kpad, int Npad, int bx, int by, int t)
{
  __shared__ float tile[32][33];
  const int tx = t & 31, ty = t >> 5;
  const int k0 = bx * 32, n0 = by * 32;
#pragma unroll
  for (int i = 0; i < 4; ++i) {
    int k = k0 + ty + i * 8, n = n0 + tx;
    tile[ty + i * 8][tx] = (k < K && n < N) ? W[(size_t)k * N + n] : 0.f;
  }
  __syncthreads();
#pragma unroll
  for (int i = 0; i < 4; ++i) {
    int n = n0 + ty + i * 8, k = k0 + tx;
    if (n < Npad && k < Kpad)
      Wt[(size_t)n * Kpad + k] = (bf16_t)tile[tx][ty + i * 8];
  }
}

__global__ __launch_bounds__(256) void prep_kernel(
    const float* __restrict__ y, bf16_t* __restrict__ X0,
    const float* __restrict__ eW1, bf16_t* __restrict__ W1t,
    const float* __restrict__ eW2, bf16_t* __restrict__ W2t,
    const float* __restrict__ eW3, bf16_t* __restrict__ W3t,
    const float* __restrict__ dW1, bf16_t* __restrict__ V1t,
    const float* __restrict__ dW2, bf16_t* __restrict__ V2t,
    const float* __restrict__ dW3, bf16_t* __restrict__ V3t)
{
  const int b = blockIdx.x;
  const int t = threadIdx.x;
  if (b < 16000) {
    const int idx = b * 256 + t;
    const int r = idx / 320, c = (idx % 320) * 8;
    bf16x8 v;
    if (c < 2520) {
      const float4 f0 = *(const float4*)(y + (size_t)r * 2520 + c);
      const float4 f1 = *(const float4*)(y + (size_t)r * 2520 + c + 4);
      v[0] = (bf16_t)f0.x; v[1] = (bf16_t)f0.y; v[2] = (bf16_t)f0.z; v[3] = (bf16_t)f0.w;
      v[4] = (bf16_t)f1.x; v[5] = (bf16_t)f1.y; v[6] = (bf16_t)f1.z; v[7] = (bf16_t)f1.w;
    } else {
#pragma unroll
      for (int j = 0; j < 8; ++j) v[j] = (bf16_t)0.f;
    }
    *(bf16x8*)(X0 + (size_t)r * 2560 + c) = v;
    return;
  }
  int lb = b - 16000;
  if (lb < 2560)      { transpose_tile(eW1, W1t, 2520, 1024, 2560, 1024, lb % 80, lb / 80, t); return; }
  lb -= 2560;
  if (lb < 1024)      { transpose_tile(eW2, W2t, 1024, 1024, 1024, 1024, lb % 32, lb / 32, t); return; }
  lb -= 1024;
  if (lb < 2048)      { transpose_tile(eW3, W3t, 1024, 2048, 1024, 2048, lb % 32, lb / 32, t); return; }
  lb -= 2048;
  if (lb < 2048)      { transpose_tile(dW1, V1t, 2048, 1024, 2048, 1024, lb % 64, lb / 64, t); return; }
  lb -= 2048;
  if (lb < 1024)      { transpose_tile(dW2, V2t, 1024, 1024, 1024, 1024, lb % 32, lb / 32, t); return; }
  lb -= 1024;
  transpose_tile(dW3, V3t, 1024, 2520, 1024, 2560, lb % 32, lb / 32, t);
}

// ---------------------------------------------------------------------------
// 256x128 GEMM, BK=32, 3 LDS slots (72KB), depth-2 prefetch, TWO blocks/CU.
// Exact tail waits (R12's race fix): vmcnt(3) steady / vmcnt(0) at NT-2 /
// none at last. No explicit lgkmcnt. Interleaved A/B ds_reads.
// ---------------------------------------------------------------------------
template<int ELU>
__global__ __launch_bounds__(512, 4) void gemm128(
    const bf16_t* __restrict__ A, const bf16_t* __restrict__ Bt,
    const float* __restrict__ bias,
    bf16_t* __restrict__ Cb, float* __restrict__ Cf,
    int M, int N, int K, int Nlog)
{
  __shared__ __align__(16) bf16_t lds[36864];

  const int t  = threadIdx.x;
  const int w  = t >> 6, l = t & 63;
  const int fr = l & 15, kg = l >> 4;
  const int wm = (w >> 1) * 64, wn = (w & 1) * 64;

  const int gx = gridDim.x;
  const int nwg = gx * (int)gridDim.y;
  int lin = blockIdx.y * gx + blockIdx.x;
  int q8 = nwg >> 3, r8 = nwg & 7, xcd = lin & 7, idx = lin >> 3;
  int swz = (xcd < r8 ? xcd * (q8 + 1) : r8 * (q8 + 1) + (xcd - r8) * q8) + idx;
  const int tn = (swz % gx) * 128;
  const int tm = (swz / gx) * 256;

  const int srow = t >> 2;
  const int scol = (t & 3) * 8;
  const int sdst = t * 8;

  const int NT = K >> 5;

  f32x4 acc[4][4];
#pragma unroll
  for (int i = 0; i < 4; ++i)
#pragma unroll
    for (int j = 0; j < 4; ++j) acc[i][j] = (f32x4){0.f, 0.f, 0.f, 0.f};

  auto stage = [&](int slot, int kn) {
    bf16_t* d = lds + slot * 12288;
    gl_lds16(A  + (size_t)(tm + srow) * K + kn + scol,       d + sdst);
    gl_lds16(A  + (size_t)(tm + 128 + srow) * K + kn + scol, d + 4096 + sdst);
    gl_lds16(Bt + (size_t)(tn + srow) * K + kn + scol,       d + 8192 + sdst);
  };

  stage(0, 0);
  stage(1, 32);
  asm volatile("s_waitcnt vmcnt(3)" ::: "memory");
  BAR();

  for (int kt = 0; kt < NT; ++kt) {
    const int slot = kt % 3;
    const bf16_t* aH = lds + slot * 12288 + wm * 32;
    const bf16_t* bH = lds + slot * 12288 + 8192 + wn * 32;

    if (kt + 2 < NT) stage((kt + 2) % 3, (kt + 2) << 5);

    bf16x8 af[4], bf_[4];
#pragma unroll
    for (int q = 0; q < 4; ++q) {
      af[q]  = *(const bf16x8*)(aH + (q * 16 + fr) * 32 + kg * 8);
      bf_[q] = *(const bf16x8*)(bH + (q * 16 + fr) * 32 + kg * 8);
    }
    __builtin_amdgcn_s_setprio(1);
#pragma unroll
    for (int mi = 0; mi < 4; ++mi)
#pragma unroll
      for (int nj = 0; nj < 4; ++nj)
        acc[mi][nj] = __builtin_amdgcn_mfma_f32_16x16x32_bf16(af[mi], bf_[nj], acc[mi][nj], 0, 0, 0);
    __builtin_amdgcn_s_setprio(0);

    if (kt + 2 < NT) {
      asm volatile("s_waitcnt vmcnt(3)" ::: "memory");
    } else if (kt + 1 < NT) {
      asm volatile("s_waitcnt vmcnt(0)" ::: "memory");
    }
    BAR();
  }

#pragma unroll
  for (int mi = 0; mi < 4; ++mi) {
    const int row0 = tm + wm + mi * 16 + kg * 4;
#pragma unroll
    for (int nj = 0; nj < 4; ++nj) {
      const int col = tn + wn + nj * 16 + fr;
      const float bv = (col < Nlog) ? bias[col] : 0.f;
#pragma unroll
      for (int r = 0; r < 4; ++r) {
        float v = acc[mi][nj][r] + bv;
        if (ELU) v = (v > 0.f) ? v : expm1f(v);
        const int row = row0 + r;
        if (Cb) Cb[(size_t)row * N + col] = (bf16_t)v;
        if (Cf && col < Nlog) Cf[(size_t)row * Nlog + col] = v;
      }
    }
  }
}

// ---------------------------------------------------------------------------
// GEMM3 + fused VQ (R15). Same K-loop as gemm128 (N=2048, no ELU, fp32 out).
// Epilogue: write ze; stash wave's 64x64 fp32 slice in wave-private LDS
// ([32][68] fp32 per half, 16B-aligned rows); then run the verified vq_mfma
// math per half: afrag from LDS, 8 code-block MFMAs, first-index-tie argmin
// butterfly, write zq (fp32 from bf16-rounded emb) + ZQb.
// LDS overlay after K-loop: seb 2048 bf16 (4KB) + 8 x 8704B wave regions
// = 73728 B exactly.
// ---------------------------------------------------------------------------
__global__ __launch_bounds__(512, 4) void gemm_vq(
    const bf16_t* __restrict__ A, const bf16_t* __restrict__ Bt,
    const float* __restrict__ bias, const float* __restrict__ emb,
    float* __restrict__ ze, float* __restrict__ zq, bf16_t* __restrict__ zqb,
    int M, int K)
{
  __shared__ __align__(16) bf16_t lds[36864];

  const int t  = threadIdx.x;
  const int w  = t >> 6, l = t & 63;
  const int fr = l & 15, kg = l >> 4;
  const int wm = (w >> 1) * 64, wn = (w & 1) * 64;

  const int gx = gridDim.x;                       // 16
  const int nwg = gx * (int)gridDim.y;
  int lin = blockIdx.y * gx + blockIdx.x;
  int q8 = nwg >> 3, r8 = nwg & 7, xcd = lin & 7, idx = lin >> 3;
  int swz = (xcd < r8 ? xcd * (q8 + 1) : r8 * (q8 + 1) + (xcd - r8) * q8) + idx;
  const int tn = (swz % gx) * 128;
  const int tm = (swz / gx) * 256;

  const int srow = t >> 2;
  const int scol = (t & 3) * 8;
  const int sdst = t * 8;

  const int NT = K >> 5;

  f32x4 acc[4][4];
#pragma unroll
  for (int i = 0; i < 4; ++i)
#pragma unroll
    for (int j = 0; j < 4; ++j) acc[i][j] = (f32x4){0.f, 0.f, 0.f, 0.f};

  auto stage = [&](int slot, int kn) {
    bf16_t* d = lds + slot * 12288;
    gl_lds16(A  + (size_t)(tm + srow) * K + kn + scol,       d + sdst);
    gl_lds16(A  + (size_t)(tm + 128 + srow) * K + kn + scol, d + 4096 + sdst);
    gl_lds16(Bt + (size_t)(tn + srow) * K + kn + scol,       d + 8192 + sdst);
  };

  stage(0, 0);
  stage(1, 32);
  asm volatile("s_waitcnt vmcnt(3)" ::: "memory");
  BAR();

  for (int kt = 0; kt < NT; ++kt) {
    const int slot = kt % 3;
    const bf16_t* aH = lds + slot * 12288 + wm * 32;
    const bf16_t* bH = lds + slot * 12288 + 8192 + wn * 32;

    if (kt + 2 < NT) stage((kt + 2) % 3, (kt + 2) << 5);

    bf16x8 af[4], bf_[4];
#pragma unroll
    for (int q = 0; q < 4; ++q) {
      af[q]  = *(const bf16x8*)(aH + (q * 16 + fr) * 32 + kg * 8);
      bf_[q] = *(const bf16x8*)(bH + (q * 16 + fr) * 32 + kg * 8);
    }
    __builtin_amdgcn_s_setprio(1);
#pragma unroll
    for (int mi = 0; mi < 4; ++mi)
#pragma unroll
      for (int nj = 0; nj < 4; ++nj)
        acc[mi][nj] = __builtin_amdgcn_mfma_f32_16x16x32_bf16(af[mi], bf_[nj], acc[mi][nj], 0, 0, 0);
    __builtin_amdgcn_s_setprio(0);

    if (kt + 2 < NT) {
      asm volatile("s_waitcnt vmcnt(3)" ::: "memory");
    } else if (kt + 1 < NT) {
      asm volatile("s_waitcnt vmcnt(0)" ::: "memory");
    }
    BAR();
  }

  // -------- epilogue: ze store + fused VQ --------
  bf16_t* seb = lds;                                      // 2048 bf16
  float*  wF  = (float*)((char*)lds + 4096 + w * 8704);   // [32][68] fp32

  // emb -> seb (bf16), all threads; then sync
  for (int i = t; i < 2048; i += 512) seb[i] = (bf16_t)emb[i];
  __syncthreads();

  const int col = fr;                 // code-/pair-lane index
  const int ks8 = kg * 8;             // 0,8,16,24
  const bool kact = (ks8 < 16);

  // per-thread hv (fp32 from global emb) + bfrag (bf16 from seb)
  float hv[8];
  bf16x8 bfrag[8];
#pragma unroll
  for (int cb = 0; cb < 8; ++cb) {
    const float* ep = emb + (cb * 16 + col) * 16;
    float s = 0.f;
#pragma unroll
    for (int j = 0; j < 16; ++j) s += ep[j] * ep[j];
    hv[cb] = 0.5f * s;
    bf16x8 bf;
#pragma unroll
    for (int j = 0; j < 8; ++j) bf[j] = (bf16_t)0.f;
    if (kact) bf = *(const bf16x8*)(seb + (cb * 16 + col) * 16 + ks8);
    bfrag[cb] = bf;
  }

#pragma unroll
  for (int h = 0; h < 2; ++h) {
    // store ze + stash slice to wave-private LDS
#pragma unroll
    for (int mi2 = 0; mi2 < 2; ++mi2) {
      const int mi = h * 2 + mi2;
      const int rl0 = mi2 * 16 + kg * 4;
      const int row0 = tm + wm + mi * 16 + kg * 4;
#pragma unroll
      for (int nj = 0; nj < 4; ++nj) {
        const int cg = tn + wn + nj * 16 + fr;
        const float bv = bias[cg];
#pragma unroll
        for (int r = 0; r < 4; ++r) {
          const float v = acc[mi][nj][r] + bv;
          ze[(size_t)(row0 + r) * 2048 + cg] = v;
          wF[(rl0 + r) * 68 + nj * 16 + fr] = v;
        }
      }
    }
    asm volatile("s_waitcnt lgkmcnt(0)" ::: "memory");   // wave-local LDS visibility

    for (int ti = 0; ti < 8; ++ti) {
      bf16x8 afrag;
#pragma unroll
      for (int j = 0; j < 8; ++j) afrag[j] = (bf16_t)0.f;
      if (kact) {
        const float* ap = wF + (ti * 4 + (col >> 2)) * 68 + (col & 3) * 16 + ks8;
        float4 a0 = *(const float4*)ap;
        float4 a1 = *(const float4*)(ap + 4);
        afrag[0] = (bf16_t)(-a0.x); afrag[1] = (bf16_t)(-a0.y);
        afrag[2] = (bf16_t)(-a0.z); afrag[3] = (bf16_t)(-a0.w);
        afrag[4] = (bf16_t)(-a1.x); afrag[5] = (bf16_t)(-a1.y);
        afrag[6] = (bf16_t)(-a1.z); afrag[7] = (bf16_t)(-a1.w);
      }

      f32x4 dd[8];
#pragma unroll
      for (int cb = 0; cb < 8; ++cb) {
        f32x4 c = (f32x4){hv[cb], hv[cb], hv[cb], hv[cb]};
        dd[cb] = __builtin_amdgcn_mfma_f32_16x16x32_bf16(afrag, bfrag[cb], c, 0, 0, 0);
      }

#pragma unroll
      for (int r2 = 0; r2 < 4; ++r2) {
        float bd = dd[0][r2]; int bi = col;
#pragma unroll
        for (int cb = 1; cb < 8; ++cb) {
          float v = dd[cb][r2];
          int   ci = cb * 16 + col;
          if (v < bd) { bd = v; bi = ci; }
        }
#pragma unroll
        for (int m = 1; m < 16; m <<= 1) {
          float od = __shfl_xor(bd, m);
          int   oi = __shfl_xor(bi, m);
          if (od < bd || (od == bd && oi < bi)) { bd = od; bi = oi; }
        }
        if (col == r2) {
          const int pair = (l >> 4) * 4 + r2;
          const size_t rg = (size_t)(tm + wm + h * 32 + ti * 4 + (pair >> 2));
          const size_t off = rg * 2048 + (tn + wn + (pair & 3) * 16);
          const bf16_t* eb = seb + bi * 16;
#pragma unroll
          for (int v4 = 0; v4 < 4; ++v4) {
            float4 f;
            f.x = (float)eb[v4 * 4 + 0]; f.y = (float)eb[v4 * 4 + 1];
            f.z = (float)eb[v4 * 4 + 2]; f.w = (float)eb[v4 * 4 + 3];
            *(float4*)(zq + off + v4 * 4) = f;
          }
          *(bf16x8*)(zqb + off)     = ((const bf16x8*)eb)[0];
          *(bf16x8*)(zqb + off + 8) = ((const bf16x8*)eb)[1];
        }
      }
    }
  }
}

// ---------------------------------------------------------------------------
extern "C" void kernel_launch(void* const* d_in, const int* in_sizes, int n_in,
                              void* d_out, int out_size, void* d_ws, size_t ws_size,
                              hipStream_t stream)
{
  const float* y   = (const float*)d_in[0];
  const float* emb = (const float*)d_in[1];
  const float* eW1 = (const float*)d_in[2];
  const float* eb1 = (const float*)d_in[3];
  const float* eW2 = (const float*)d_in[4];
  const float* eb2 = (const float*)d_in[5];
  const float* eW3 = (const float*)d_in[6];
  const float* eb3 = (const float*)d_in[7];
  const float* dW1 = (const float*)d_in[8];
  const float* db1 = (const float*)d_in[9];
  const float* dW2 = (const float*)d_in[10];
  const float* db2 = (const float*)d_in[11];
  const float* dW3 = (const float*)d_in[12];
  const float* db3 = (const float*)d_in[13];

  float* out = (float*)d_out;               // [12800][2520]
  float* ze  = out + 32256000;              // [12800][2048]
  float* zq  = ze + 26214400;               // [12800][2048]

  uint8_t* ws = (uint8_t*)d_ws;
  size_t off = 0;
  auto alloc = [&](size_t bytes) -> void* {
    void* p = ws + off; off += (bytes + 255) & ~(size_t)255; return p;
  };
  bf16_t* X0  = (bf16_t*)alloc(12800ULL * 2560 * 2);
  bf16_t* W1t = (bf16_t*)alloc(1024ULL * 2560 * 2);
  bf16_t* W2t = (bf16_t*)alloc(1024ULL * 1024 * 2);
  bf16_t* W3t = (bf16_t*)alloc(2048ULL * 1024 * 2);
  bf16_t* V1t = (bf16_t*)alloc(1024ULL * 2048 * 2);
  bf16_t* V2t = (bf16_t*)alloc(1024ULL * 1024 * 2);
  bf16_t* V3t = (bf16_t*)alloc(2560ULL * 1024 * 2);
  bf16_t* H1  = (bf16_t*)alloc(12800ULL * 1024 * 2);
  bf16_t* H2  = (bf16_t*)alloc(12800ULL * 1024 * 2);
  bf16_t* ZQb = (bf16_t*)alloc(12800ULL * 2048 * 2);

  prep_kernel<<<27264, 256, 0, stream>>>(y, X0, eW1, W1t, eW2, W2t, eW3, W3t,
                                         dW1, V1t, dW2, V2t, dW3, V3t);

  // encoder
  gemm128<1><<<dim3(8, 50), 512, 0, stream>>>(X0, W1t, eb1, H1, nullptr, 12800, 1024, 2560, 1024);
  gemm128<1><<<dim3(8, 50), 512, 0, stream>>>(H1, W2t, eb2, H2, nullptr, 12800, 1024, 1024, 1024);
  // GEMM3 + fused VQ
  gemm_vq<<<dim3(16, 50), 512, 0, stream>>>(H2, W3t, eb3, emb, ze, zq, ZQb, 12800, 1024);
  // decoder
  gemm128<1><<<dim3(8, 50), 512, 0, stream>>>(ZQb, V1t, db1, H1, nullptr, 12800, 1024, 2048, 1024);
  gemm128<1><<<dim3(8, 50), 512, 0, stream>>>(H1, V2t, db2, H2, nullptr, 12800, 1024, 1024, 1024);
  gemm128<0><<<dim3(20, 50), 512, 0, stream>>>(H2, V3t, db3, nullptr, out, 12800, 2560, 1024, 2520);
}

// Round 16
// 595.115 us; speedup vs baseline: 1.6528x; 1.6528x over previous
//
#include <hip/hip_runtime.h>
#include <hip/hip_bf16.h>
#include <cstdint>
#include <cstddef>

typedef __bf16 bf16_t;
typedef bf16_t bf16x8 __attribute__((ext_vector_type(8)));
typedef float  f32x4  __attribute__((ext_vector_type(4)));

__device__ __forceinline__ void gl_lds16(const void* g, void* l) {
  __builtin_amdgcn_global_load_lds(
      (const __attribute__((address_space(1))) void*)g,
      (__attribute__((address_space(3))) void*)l, 16, 0, 0);
}

#define BAR()  __builtin_amdgcn_s_barrier()

// ---------------------------------------------------------------------------
// prep kernel: fused pack_x0 + 6 weight transposes (fp32 -> bf16, KxN -> Npad x Kpad)
// ---------------------------------------------------------------------------
__device__ __forceinline__ void transpose_tile(
    const float* __restrict__ W, bf16_t* __restrict__ Wt,
    int K, int N, int Kpad, int Npad, int bx, int by, int t)
{
  __shared__ float tile[32][33];
  const int tx = t & 31, ty = t >> 5;
  const int k0 = bx * 32, n0 = by * 32;
#pragma unroll
  for (int i = 0; i < 4; ++i) {
    int k = k0 + ty + i * 8, n = n0 + tx;
    tile[ty + i * 8][tx] = (k < K && n < N) ? W[(size_t)k * N + n] : 0.f;
  }
  __syncthreads();
#pragma unroll
  for (int i = 0; i < 4; ++i) {
    int n = n0 + ty + i * 8, k = k0 + tx;
    if (n < Npad && k < Kpad)
      Wt[(size_t)n * Kpad + k] = (bf16_t)tile[tx][ty + i * 8];
  }
}

__global__ __launch_bounds__(256) void prep_kernel(
    const float* __restrict__ y, bf16_t* __restrict__ X0,
    const float* __restrict__ eW1, bf16_t* __restrict__ W1t,
    const float* __restrict__ eW2, bf16_t* __restrict__ W2t,
    const float* __restrict__ eW3, bf16_t* __restrict__ W3t,
    const float* __restrict__ dW1, bf16_t* __restrict__ V1t,
    const float* __restrict__ dW2, bf16_t* __restrict__ V2t,
    const float* __restrict__ dW3, bf16_t* __restrict__ V3t)
{
  const int b = blockIdx.x;
  const int t = threadIdx.x;
  if (b < 16000) {
    const int idx = b * 256 + t;
    const int r = idx / 320, c = (idx % 320) * 8;
    bf16x8 v;
    if (c < 2520) {
      const float4 f0 = *(const float4*)(y + (size_t)r * 2520 + c);
      const float4 f1 = *(const float4*)(y + (size_t)r * 2520 + c + 4);
      v[0] = (bf16_t)f0.x; v[1] = (bf16_t)f0.y; v[2] = (bf16_t)f0.z; v[3] = (bf16_t)f0.w;
      v[4] = (bf16_t)f1.x; v[5] = (bf16_t)f1.y; v[6] = (bf16_t)f1.z; v[7] = (bf16_t)f1.w;
    } else {
#pragma unroll
      for (int j = 0; j < 8; ++j) v[j] = (bf16_t)0.f;
    }
    *(bf16x8*)(X0 + (size_t)r * 2560 + c) = v;
    return;
  }
  int lb = b - 16000;
  if (lb < 2560)      { transpose_tile(eW1, W1t, 2520, 1024, 2560, 1024, lb % 80, lb / 80, t); return; }
  lb -= 2560;
  if (lb < 1024)      { transpose_tile(eW2, W2t, 1024, 1024, 1024, 1024, lb % 32, lb / 32, t); return; }
  lb -= 1024;
  if (lb < 2048)      { transpose_tile(eW3, W3t, 1024, 2048, 1024, 2048, lb % 32, lb / 32, t); return; }
  lb -= 2048;
  if (lb < 2048)      { transpose_tile(dW1, V1t, 2048, 1024, 2048, 1024, lb % 64, lb / 64, t); return; }
  lb -= 2048;
  if (lb < 1024)      { transpose_tile(dW2, V2t, 1024, 1024, 1024, 1024, lb % 32, lb / 32, t); return; }
  lb -= 1024;
  transpose_tile(dW3, V3t, 1024, 2520, 1024, 2560, lb % 32, lb / 32, t);
}

// ---------------------------------------------------------------------------
// 256x128 GEMM, BK=32, 3 LDS slots (72KB), depth-2 prefetch, TWO blocks/CU.
// Exact tail waits: vmcnt(3) steady / vmcnt(0) at NT-2 / none at last.
// ---------------------------------------------------------------------------
template<int ELU>
__global__ __launch_bounds__(512, 4) void gemm128(
    const bf16_t* __restrict__ A, const bf16_t* __restrict__ Bt,
    const float* __restrict__ bias,
    bf16_t* __restrict__ Cb, float* __restrict__ Cf,
    int M, int N, int K, int Nlog)
{
  __shared__ __align__(16) bf16_t lds[36864];

  const int t  = threadIdx.x;
  const int w  = t >> 6, l = t & 63;
  const int fr = l & 15, kg = l >> 4;
  const int wm = (w >> 1) * 64, wn = (w & 1) * 64;

  const int gx = gridDim.x;
  const int nwg = gx * (int)gridDim.y;
  int lin = blockIdx.y * gx + blockIdx.x;
  int q8 = nwg >> 3, r8 = nwg & 7, xcd = lin & 7, idx = lin >> 3;
  int swz = (xcd < r8 ? xcd * (q8 + 1) : r8 * (q8 + 1) + (xcd - r8) * q8) + idx;
  const int tn = (swz % gx) * 128;
  const int tm = (swz / gx) * 256;

  const int srow = t >> 2;
  const int scol = (t & 3) * 8;
  const int sdst = t * 8;

  const int NT = K >> 5;

  f32x4 acc[4][4];
#pragma unroll
  for (int i = 0; i < 4; ++i)
#pragma unroll
    for (int j = 0; j < 4; ++j) acc[i][j] = (f32x4){0.f, 0.f, 0.f, 0.f};

  auto stage = [&](int slot, int kn) {
    bf16_t* d = lds + slot * 12288;
    gl_lds16(A  + (size_t)(tm + srow) * K + kn + scol,       d + sdst);
    gl_lds16(A  + (size_t)(tm + 128 + srow) * K + kn + scol, d + 4096 + sdst);
    gl_lds16(Bt + (size_t)(tn + srow) * K + kn + scol,       d + 8192 + sdst);
  };

  stage(0, 0);
  stage(1, 32);
  asm volatile("s_waitcnt vmcnt(3)" ::: "memory");
  BAR();

  for (int kt = 0; kt < NT; ++kt) {
    const int slot = kt % 3;
    const bf16_t* aH = lds + slot * 12288 + wm * 32;
    const bf16_t* bH = lds + slot * 12288 + 8192 + wn * 32;

    if (kt + 2 < NT) stage((kt + 2) % 3, (kt + 2) << 5);

    bf16x8 af[4], bf_[4];
#pragma unroll
    for (int q = 0; q < 4; ++q) {
      af[q]  = *(const bf16x8*)(aH + (q * 16 + fr) * 32 + kg * 8);
      bf_[q] = *(const bf16x8*)(bH + (q * 16 + fr) * 32 + kg * 8);
    }
    __builtin_amdgcn_s_setprio(1);
#pragma unroll
    for (int mi = 0; mi < 4; ++mi)
#pragma unroll
      for (int nj = 0; nj < 4; ++nj)
        acc[mi][nj] = __builtin_amdgcn_mfma_f32_16x16x32_bf16(af[mi], bf_[nj], acc[mi][nj], 0, 0, 0);
    __builtin_amdgcn_s_setprio(0);

    if (kt + 2 < NT) {
      asm volatile("s_waitcnt vmcnt(3)" ::: "memory");
    } else if (kt + 1 < NT) {
      asm volatile("s_waitcnt vmcnt(0)" ::: "memory");
    }
    BAR();
  }

#pragma unroll
  for (int mi = 0; mi < 4; ++mi) {
    const int row0 = tm + wm + mi * 16 + kg * 4;
#pragma unroll
    for (int nj = 0; nj < 4; ++nj) {
      const int col = tn + wn + nj * 16 + fr;
      const float bv = (col < Nlog) ? bias[col] : 0.f;
#pragma unroll
      for (int r = 0; r < 4; ++r) {
        float v = acc[mi][nj][r] + bv;
        if (ELU) v = (v > 0.f) ? v : expm1f(v);
        const int row = row0 + r;
        if (Cb) Cb[(size_t)row * N + col] = (bf16_t)v;
        if (Cf && col < Nlog) Cf[(size_t)row * Nlog + col] = v;
      }
    }
  }
}

// ---------------------------------------------------------------------------
// GEMM3 + fused VQ, register-light epilogue (R16).
// R15's lesson: acc (64 AGPR) + epilogue arrays blew the 128-reg cap -> 1GB
// scratch. Fix: stream codes one cb at a time -- per cb one bfrag ds_read
// (seb), one hv ds_read (shv table), one MFMA, fold into running bd[4]/bi[4].
// Peak epilogue VGPR ~45 <= 64 available beside the AGPR acc.
// LDS after K-loop: seb 2048 bf16 (4KB) + shv 128 f32 (512B) + 8 x wF
// ([32][68] f32 = 8704B, 16B-aligned rows) = 74240 B (<=80KB -> 2 blocks/CU).
// Min-update runs on ALL lanes (C/D layout: every lane holds valid dists;
// kact gates only the K-split input loads). First-index tie-break preserved.
// ---------------------------------------------------------------------------
__global__ __launch_bounds__(512, 4) void gemm_vq(
    const bf16_t* __restrict__ A, const bf16_t* __restrict__ Bt,
    const float* __restrict__ bias, const float* __restrict__ emb,
    float* __restrict__ ze, float* __restrict__ zq, bf16_t* __restrict__ zqb,
    int M, int K)
{
  __shared__ __align__(16) bf16_t lds[37120];   // 74240 B

  const int t  = threadIdx.x;
  const int w  = t >> 6, l = t & 63;
  const int fr = l & 15, kg = l >> 4;
  const int wm = (w >> 1) * 64, wn = (w & 1) * 64;

  const int gx = gridDim.x;                       // 16
  const int nwg = gx * (int)gridDim.y;
  int lin = blockIdx.y * gx + blockIdx.x;
  int q8 = nwg >> 3, r8 = nwg & 7, xcd = lin & 7, idx = lin >> 3;
  int swz = (xcd < r8 ? xcd * (q8 + 1) : r8 * (q8 + 1) + (xcd - r8) * q8) + idx;
  const int tn = (swz % gx) * 128;
  const int tm = (swz / gx) * 256;

  const int srow = t >> 2;
  const int scol = (t & 3) * 8;
  const int sdst = t * 8;

  const int NT = K >> 5;

  f32x4 acc[4][4];
#pragma unroll
  for (int i = 0; i < 4; ++i)
#pragma unroll
    for (int j = 0; j < 4; ++j) acc[i][j] = (f32x4){0.f, 0.f, 0.f, 0.f};

  auto stage = [&](int slot, int kn) {
    bf16_t* d = lds + slot * 12288;
    gl_lds16(A  + (size_t)(tm + srow) * K + kn + scol,       d + sdst);
    gl_lds16(A  + (size_t)(tm + 128 + srow) * K + kn + scol, d + 4096 + sdst);
    gl_lds16(Bt + (size_t)(tn + srow) * K + kn + scol,       d + 8192 + sdst);
  };

  stage(0, 0);
  stage(1, 32);
  asm volatile("s_waitcnt vmcnt(3)" ::: "memory");
  BAR();

  for (int kt = 0; kt < NT; ++kt) {
    const int slot = kt % 3;
    const bf16_t* aH = lds + slot * 12288 + wm * 32;
    const bf16_t* bH = lds + slot * 12288 + 8192 + wn * 32;

    if (kt + 2 < NT) stage((kt + 2) % 3, (kt + 2) << 5);

    bf16x8 af[4], bf_[4];
#pragma unroll
    for (int q = 0; q < 4; ++q) {
      af[q]  = *(const bf16x8*)(aH + (q * 16 + fr) * 32 + kg * 8);
      bf_[q] = *(const bf16x8*)(bH + (q * 16 + fr) * 32 + kg * 8);
    }
    __builtin_amdgcn_s_setprio(1);
#pragma unroll
    for (int mi = 0; mi < 4; ++mi)
#pragma unroll
      for (int nj = 0; nj < 4; ++nj)
        acc[mi][nj] = __builtin_amdgcn_mfma_f32_16x16x32_bf16(af[mi], bf_[nj], acc[mi][nj], 0, 0, 0);
    __builtin_amdgcn_s_setprio(0);

    if (kt + 2 < NT) {
      asm volatile("s_waitcnt vmcnt(3)" ::: "memory");
    } else if (kt + 1 < NT) {
      asm volatile("s_waitcnt vmcnt(0)" ::: "memory");
    }
    BAR();
  }

  // -------- epilogue: ze store + fused VQ (register-light) --------
  bf16_t* seb = lds;                                      // [2048] bf16
  float*  shv = (float*)(lds + 2048);                     // [128]  f32 @4096
  float*  wF  = (float*)((char*)lds + 4608 + w * 8704);   // [32][68] f32

  for (int i = t; i < 2048; i += 512) seb[i] = (bf16_t)emb[i];
  if (t < 128) {
    const float* ep = emb + t * 16;
    float s = 0.f;
#pragma unroll
    for (int j = 0; j < 16; ++j) s += ep[j] * ep[j];
    shv[t] = 0.5f * s;
  }
  __syncthreads();

  const int col = fr;
  const int ks8 = kg * 8;
  const bool kact = (ks8 < 16);

#pragma unroll
  for (int h = 0; h < 2; ++h) {
    // store ze + stash wave slice to wave-private LDS
#pragma unroll
    for (int mi2 = 0; mi2 < 2; ++mi2) {
      const int mi = h * 2 + mi2;
      const int rl0 = mi2 * 16 + kg * 4;
      const int row0 = tm + wm + mi * 16 + kg * 4;
#pragma unroll
      for (int nj = 0; nj < 4; ++nj) {
        const int cg = tn + wn + nj * 16 + fr;
        const float bv = bias[cg];
#pragma unroll
        for (int r = 0; r < 4; ++r) {
          const float v = acc[mi][nj][r] + bv;
          ze[(size_t)(row0 + r) * 2048 + cg] = v;
          wF[(rl0 + r) * 68 + nj * 16 + fr] = v;
        }
      }
    }
    asm volatile("s_waitcnt lgkmcnt(0)" ::: "memory");   // wave-local LDS visibility

    for (int ti = 0; ti < 8; ++ti) {
      bf16x8 afrag;
#pragma unroll
      for (int j = 0; j < 8; ++j) afrag[j] = (bf16_t)0.f;
      if (kact) {
        const float* ap = wF + (ti * 4 + (col >> 2)) * 68 + (col & 3) * 16 + ks8;
        float4 a0 = *(const float4*)ap;
        float4 a1 = *(const float4*)(ap + 4);
        afrag[0] = (bf16_t)(-a0.x); afrag[1] = (bf16_t)(-a0.y);
        afrag[2] = (bf16_t)(-a0.z); afrag[3] = (bf16_t)(-a0.w);
        afrag[4] = (bf16_t)(-a1.x); afrag[5] = (bf16_t)(-a1.y);
        afrag[6] = (bf16_t)(-a1.z); afrag[7] = (bf16_t)(-a1.w);
      }

      float bd[4] = {1e30f, 1e30f, 1e30f, 1e30f};
      int   bi[4] = {0, 0, 0, 0};
#pragma unroll
      for (int cb = 0; cb < 8; ++cb) {
        bf16x8 bf;
#pragma unroll
        for (int j = 0; j < 8; ++j) bf[j] = (bf16_t)0.f;
        if (kact) bf = *(const bf16x8*)(seb + (cb * 16 + col) * 16 + ks8);
        const float hvv = shv[cb * 16 + col];
        f32x4 c = (f32x4){hvv, hvv, hvv, hvv};
        f32x4 dd = __builtin_amdgcn_mfma_f32_16x16x32_bf16(afrag, bf, c, 0, 0, 0);
        const int ci = cb * 16 + col;
#pragma unroll
        for (int r2 = 0; r2 < 4; ++r2)
          if (dd[r2] < bd[r2]) { bd[r2] = dd[r2]; bi[r2] = ci; }
      }

#pragma unroll
      for (int r2 = 0; r2 < 4; ++r2) {
        float bdv = bd[r2]; int biv = bi[r2];
#pragma unroll
        for (int m = 1; m < 16; m <<= 1) {
          float od = __shfl_xor(bdv, m);
          int   oi = __shfl_xor(biv, m);
          if (od < bdv || (od == bdv && oi < biv)) { bdv = od; biv = oi; }
        }
        if (col == r2) {
          const int pair = kg * 4 + r2;
          const size_t rg = (size_t)(tm + wm + h * 32 + ti * 4 + (pair >> 2));
          const size_t off = rg * 2048 + (tn + wn + (pair & 3) * 16);
          const bf16_t* eb = seb + biv * 16;
#pragma unroll
          for (int v4 = 0; v4 < 4; ++v4) {
            float4 f;
            f.x = (float)eb[v4 * 4 + 0]; f.y = (float)eb[v4 * 4 + 1];
            f.z = (float)eb[v4 * 4 + 2]; f.w = (float)eb[v4 * 4 + 3];
            *(float4*)(zq + off + v4 * 4) = f;
          }
          *(bf16x8*)(zqb + off)     = ((const bf16x8*)eb)[0];
          *(bf16x8*)(zqb + off + 8) = ((const bf16x8*)eb)[1];
        }
      }
    }
  }
}

// ---------------------------------------------------------------------------
extern "C" void kernel_launch(void* const* d_in, const int* in_sizes, int n_in,
                              void* d_out, int out_size, void* d_ws, size_t ws_size,
                              hipStream_t stream)
{
  const float* y   = (const float*)d_in[0];
  const float* emb = (const float*)d_in[1];
  const float* eW1 = (const float*)d_in[2];
  const float* eb1 = (const float*)d_in[3];
  const float* eW2 = (const float*)d_in[4];
  const float* eb2 = (const float*)d_in[5];
  const float* eW3 = (const float*)d_in[6];
  const float* eb3 = (const float*)d_in[7];
  const float* dW1 = (const float*)d_in[8];
  const float* db1 = (const float*)d_in[9];
  const float* dW2 = (const float*)d_in[10];
  const float* db2 = (const float*)d_in[11];
  const float* dW3 = (const float*)d_in[12];
  const float* db3 = (const float*)d_in[13];

  float* out = (float*)d_out;               // [12800][2520]
  float* ze  = out + 32256000;              // [12800][2048]
  float* zq  = ze + 26214400;               // [12800][2048]

  uint8_t* ws = (uint8_t*)d_ws;
  size_t off = 0;
  auto alloc = [&](size_t bytes) -> void* {
    void* p = ws + off; off += (bytes + 255) & ~(size_t)255; return p;
  };
  bf16_t* X0  = (bf16_t*)alloc(12800ULL * 2560 * 2);
  bf16_t* W1t = (bf16_t*)alloc(1024ULL * 2560 * 2);
  bf16_t* W2t = (bf16_t*)alloc(1024ULL * 1024 * 2);
  bf16_t* W3t = (bf16_t*)alloc(2048ULL * 1024 * 2);
  bf16_t* V1t = (bf16_t*)alloc(1024ULL * 2048 * 2);
  bf16_t* V2t = (bf16_t*)alloc(1024ULL * 1024 * 2);
  bf16_t* V3t = (bf16_t*)alloc(2560ULL * 1024 * 2);
  bf16_t* H1  = (bf16_t*)alloc(12800ULL * 1024 * 2);
  bf16_t* H2  = (bf16_t*)alloc(12800ULL * 1024 * 2);
  bf16_t* ZQb = (bf16_t*)alloc(12800ULL * 2048 * 2);

  prep_kernel<<<27264, 256, 0, stream>>>(y, X0, eW1, W1t, eW2, W2t, eW3, W3t,
                                         dW1, V1t, dW2, V2t, dW3, V3t);

  // encoder
  gemm128<1><<<dim3(8, 50), 512, 0, stream>>>(X0, W1t, eb1, H1, nullptr, 12800, 1024, 2560, 1024);
  gemm128<1><<<dim3(8, 50), 512, 0, stream>>>(H1, W2t, eb2, H2, nullptr, 12800, 1024, 1024, 1024);
  // GEMM3 + fused VQ
  gemm_vq<<<dim3(16, 50), 512, 0, stream>>>(H2, W3t, eb3, emb, ze, zq, ZQb, 12800, 1024);
  // decoder
  gemm128<1><<<dim3(8, 50), 512, 0, stream>>>(ZQb, V1t, db1, H1, nullptr, 12800, 1024, 2048, 1024);
  gemm128<1><<<dim3(8, 50), 512, 0, stream>>>(H1, V2t, db2, H2, nullptr, 12800, 1024, 1024, 1024);
  gemm128<0><<<dim3(20, 50), 512, 0, stream>>>(H2, V3t, db3, nullptr, out, 12800, 2560, 1024, 2520);
}

// Round 17
// 577.207 us; speedup vs baseline: 1.7041x; 1.0310x over previous
//
#include <hip/hip_runtime.h>
#include <hip/hip_bf16.h>
#include <cstdint>
#include <cstddef>

typedef __bf16 bf16_t;
typedef bf16_t bf16x8 __attribute__((ext_vector_type(8)));
typedef float  f32x4  __attribute__((ext_vector_type(4)));

__device__ __forceinline__ void gl_lds16(const void* g, void* l) {
  __builtin_amdgcn_global_load_lds(
      (const __attribute__((address_space(1))) void*)g,
      (__attribute__((address_space(3))) void*)l, 16, 0, 0);
}

#define BAR()  __builtin_amdgcn_s_barrier()

// ---------------------------------------------------------------------------
// prep kernel: fused pack_x0 + 6 weight transposes (fp32 -> bf16, KxN -> Npad x Kpad)
// ---------------------------------------------------------------------------
__device__ __forceinline__ void transpose_tile(
    const float* __restrict__ W, bf16_t* __restrict__ Wt,
    int K, int N, int Kpad, int Npad, int bx, int by, int t)
{
  __shared__ float tile[32][33];
  const int tx = t & 31, ty = t >> 5;
  const int k0 = bx * 32, n0 = by * 32;
#pragma unroll
  for (int i = 0; i < 4; ++i) {
    int k = k0 + ty + i * 8, n = n0 + tx;
    tile[ty + i * 8][tx] = (k < K && n < N) ? W[(size_t)k * N + n] : 0.f;
  }
  __syncthreads();
#pragma unroll
  for (int i = 0; i < 4; ++i) {
    int n = n0 + ty + i * 8, k = k0 + tx;
    if (n < Npad && k < Kpad)
      Wt[(size_t)n * Kpad + k] = (bf16_t)tile[tx][ty + i * 8];
  }
}

__global__ __launch_bounds__(256) void prep_kernel(
    const float* __restrict__ y, bf16_t* __restrict__ X0,
    const float* __restrict__ eW1, bf16_t* __restrict__ W1t,
    const float* __restrict__ eW2, bf16_t* __restrict__ W2t,
    const float* __restrict__ eW3, bf16_t* __restrict__ W3t,
    const float* __restrict__ dW1, bf16_t* __restrict__ V1t,
    const float* __restrict__ dW2, bf16_t* __restrict__ V2t,
    const float* __restrict__ dW3, bf16_t* __restrict__ V3t)
{
  const int b = blockIdx.x;
  const int t = threadIdx.x;
  if (b < 16000) {
    const int idx = b * 256 + t;
    const int r = idx / 320, c = (idx % 320) * 8;
    bf16x8 v;
    if (c < 2520) {
      const float4 f0 = *(const float4*)(y + (size_t)r * 2520 + c);
      const float4 f1 = *(const float4*)(y + (size_t)r * 2520 + c + 4);
      v[0] = (bf16_t)f0.x; v[1] = (bf16_t)f0.y; v[2] = (bf16_t)f0.z; v[3] = (bf16_t)f0.w;
      v[4] = (bf16_t)f1.x; v[5] = (bf16_t)f1.y; v[6] = (bf16_t)f1.z; v[7] = (bf16_t)f1.w;
    } else {
#pragma unroll
      for (int j = 0; j < 8; ++j) v[j] = (bf16_t)0.f;
    }
    *(bf16x8*)(X0 + (size_t)r * 2560 + c) = v;
    return;
  }
  int lb = b - 16000;
  if (lb < 2560)      { transpose_tile(eW1, W1t, 2520, 1024, 2560, 1024, lb % 80, lb / 80, t); return; }
  lb -= 2560;
  if (lb < 1024)      { transpose_tile(eW2, W2t, 1024, 1024, 1024, 1024, lb % 32, lb / 32, t); return; }
  lb -= 1024;
  if (lb < 2048)      { transpose_tile(eW3, W3t, 1024, 2048, 1024, 2048, lb % 32, lb / 32, t); return; }
  lb -= 2048;
  if (lb < 2048)      { transpose_tile(dW1, V1t, 2048, 1024, 2048, 1024, lb % 64, lb / 64, t); return; }
  lb -= 2048;
  if (lb < 1024)      { transpose_tile(dW2, V2t, 1024, 1024, 1024, 1024, lb % 32, lb / 32, t); return; }
  lb -= 1024;
  transpose_tile(dW3, V3t, 1024, 2520, 1024, 2560, lb % 32, lb / 32, t);
}

// ---------------------------------------------------------------------------
// 256x128 GEMM, BK=32, 3 LDS slots (72KB), depth-2 prefetch, TWO blocks/CU.
// Exact tail waits: vmcnt(3) steady / vmcnt(0) at NT-2 / none at last.
// R17: LDS-roundtrip epilogue -- stash tile in wave-private LDS (reusing the
// dead staging slots after the final barrier), read back row-major, store
// coalesced (bf16x8 / float4) instead of 64 scalar stores per thread.
// bf16: [32][72] bf16/wave (4608B), 2 half-passes. f32: [32][72] f32 (9216B).
// ---------------------------------------------------------------------------
template<int ELU>
__global__ __launch_bounds__(512, 4) void gemm128(
    const bf16_t* __restrict__ A, const bf16_t* __restrict__ Bt,
    const float* __restrict__ bias,
    bf16_t* __restrict__ Cb, float* __restrict__ Cf,
    int M, int N, int K, int Nlog)
{
  __shared__ __align__(16) bf16_t lds[36864];

  const int t  = threadIdx.x;
  const int w  = t >> 6, l = t & 63;
  const int fr = l & 15, kg = l >> 4;
  const int wm = (w >> 1) * 64, wn = (w & 1) * 64;

  const int gx = gridDim.x;
  const int nwg = gx * (int)gridDim.y;
  int lin = blockIdx.y * gx + blockIdx.x;
  int q8 = nwg >> 3, r8 = nwg & 7, xcd = lin & 7, idx = lin >> 3;
  int swz = (xcd < r8 ? xcd * (q8 + 1) : r8 * (q8 + 1) + (xcd - r8) * q8) + idx;
  const int tn = (swz % gx) * 128;
  const int tm = (swz / gx) * 256;

  const int srow = t >> 2;
  const int scol = (t & 3) * 8;
  const int sdst = t * 8;

  const int NT = K >> 5;

  f32x4 acc[4][4];
#pragma unroll
  for (int i = 0; i < 4; ++i)
#pragma unroll
    for (int j = 0; j < 4; ++j) acc[i][j] = (f32x4){0.f, 0.f, 0.f, 0.f};

  auto stage = [&](int slot, int kn) {
    bf16_t* d = lds + slot * 12288;
    gl_lds16(A  + (size_t)(tm + srow) * K + kn + scol,       d + sdst);
    gl_lds16(A  + (size_t)(tm + 128 + srow) * K + kn + scol, d + 4096 + sdst);
    gl_lds16(Bt + (size_t)(tn + srow) * K + kn + scol,       d + 8192 + sdst);
  };

  stage(0, 0);
  stage(1, 32);
  asm volatile("s_waitcnt vmcnt(3)" ::: "memory");
  BAR();

  for (int kt = 0; kt < NT; ++kt) {
    const int slot = kt % 3;
    const bf16_t* aH = lds + slot * 12288 + wm * 32;
    const bf16_t* bH = lds + slot * 12288 + 8192 + wn * 32;

    if (kt + 2 < NT) stage((kt + 2) % 3, (kt + 2) << 5);

    bf16x8 af[4], bf_[4];
#pragma unroll
    for (int q = 0; q < 4; ++q) {
      af[q]  = *(const bf16x8*)(aH + (q * 16 + fr) * 32 + kg * 8);
      bf_[q] = *(const bf16x8*)(bH + (q * 16 + fr) * 32 + kg * 8);
    }
    __builtin_amdgcn_s_setprio(1);
#pragma unroll
    for (int mi = 0; mi < 4; ++mi)
#pragma unroll
      for (int nj = 0; nj < 4; ++nj)
        acc[mi][nj] = __builtin_amdgcn_mfma_f32_16x16x32_bf16(af[mi], bf_[nj], acc[mi][nj], 0, 0, 0);
    __builtin_amdgcn_s_setprio(0);

    if (kt + 2 < NT) {
      asm volatile("s_waitcnt vmcnt(3)" ::: "memory");
    } else if (kt + 1 < NT) {
      asm volatile("s_waitcnt vmcnt(0)" ::: "memory");
    }
    BAR();
  }

  // -------- epilogue via LDS roundtrip (slots are dead after final BAR) -----
  if (Cb) {
    bf16_t* wB = lds + w * 2304;            // [32][72] bf16 per wave
#pragma unroll
    for (int h = 0; h < 2; ++h) {
#pragma unroll
      for (int mi2 = 0; mi2 < 2; ++mi2) {
        const int mi = h * 2 + mi2;
        const int rl0 = mi2 * 16 + kg * 4;
#pragma unroll
        for (int nj = 0; nj < 4; ++nj) {
          const int cl = nj * 16 + fr;
          const float bv = bias[tn + wn + cl];
#pragma unroll
          for (int r = 0; r < 4; ++r) {
            float v = acc[mi][nj][r] + bv;
            if (ELU) v = (v > 0.f) ? v : expm1f(v);
            wB[(rl0 + r) * 72 + cl] = (bf16_t)v;
          }
        }
      }
      asm volatile("s_waitcnt lgkmcnt(0)" ::: "memory");
#pragma unroll
      for (int j = 0; j < 4; ++j) {
        const int rl = j * 8 + (l >> 3);
        const int cl = (l & 7) * 8;
        bf16x8 v = *(const bf16x8*)(wB + rl * 72 + cl);
        *(bf16x8*)(Cb + (size_t)(tm + wm + h * 32 + rl) * N + tn + wn + cl) = v;
      }
      asm volatile("s_waitcnt lgkmcnt(0)" ::: "memory");
    }
  } else {
    float* wFo = (float*)lds + w * 2304;    // [32][72] f32 per wave
#pragma unroll
    for (int h = 0; h < 2; ++h) {
#pragma unroll
      for (int mi2 = 0; mi2 < 2; ++mi2) {
        const int mi = h * 2 + mi2;
        const int rl0 = mi2 * 16 + kg * 4;
#pragma unroll
        for (int nj = 0; nj < 4; ++nj) {
          const int cl = nj * 16 + fr;
          const int col = tn + wn + cl;
          const float bv = (col < Nlog) ? bias[col] : 0.f;
#pragma unroll
          for (int r = 0; r < 4; ++r)
            wFo[(rl0 + r) * 72 + cl] = acc[mi][nj][r] + bv;
        }
      }
      asm volatile("s_waitcnt lgkmcnt(0)" ::: "memory");
#pragma unroll
      for (int j = 0; j < 8; ++j) {
        const int rl = j * 4 + (l >> 4);
        const int cl = (l & 15) * 4;
        const int col = tn + wn + cl;
        float4 v = *(const float4*)(wFo + rl * 72 + cl);
        const size_t base = (size_t)(tm + wm + h * 32 + rl) * Nlog;
        if (col + 3 < Nlog) {
          *(float4*)(Cf + base + col) = v;
        } else {
          if (col + 0 < Nlog) Cf[base + col + 0] = v.x;
          if (col + 1 < Nlog) Cf[base + col + 1] = v.y;
          if (col + 2 < Nlog) Cf[base + col + 2] = v.z;
        }
      }
      asm volatile("s_waitcnt lgkmcnt(0)" ::: "memory");
    }
  }
}

// ---------------------------------------------------------------------------
// GEMM3 + fused VQ, register-light streaming epilogue (R16) + coalesced ze
// stores via the wF stash (R17). wF stride 72 f32 (288B rows, 16B-aligned).
// LDS: seb 2048 bf16 (4KB) + shv pad to 4608 + 8 x [32][72] f32 (9216B)
// = 78336 B  (2 blocks/CU retained: 2x78336 <= 160KB).
// ---------------------------------------------------------------------------
__global__ __launch_bounds__(512, 4) void gemm_vq(
    const bf16_t* __restrict__ A, const bf16_t* __restrict__ Bt,
    const float* __restrict__ bias, const float* __restrict__ emb,
    float* __restrict__ ze, float* __restrict__ zq, bf16_t* __restrict__ zqb,
    int M, int K)
{
  __shared__ __align__(16) bf16_t lds[39168];   // 78336 B

  const int t  = threadIdx.x;
  const int w  = t >> 6, l = t & 63;
  const int fr = l & 15, kg = l >> 4;
  const int wm = (w >> 1) * 64, wn = (w & 1) * 64;

  const int gx = gridDim.x;                       // 16
  const int nwg = gx * (int)gridDim.y;
  int lin = blockIdx.y * gx + blockIdx.x;
  int q8 = nwg >> 3, r8 = nwg & 7, xcd = lin & 7, idx = lin >> 3;
  int swz = (xcd < r8 ? xcd * (q8 + 1) : r8 * (q8 + 1) + (xcd - r8) * q8) + idx;
  const int tn = (swz % gx) * 128;
  const int tm = (swz / gx) * 256;

  const int srow = t >> 2;
  const int scol = (t & 3) * 8;
  const int sdst = t * 8;

  const int NT = K >> 5;

  f32x4 acc[4][4];
#pragma unroll
  for (int i = 0; i < 4; ++i)
#pragma unroll
    for (int j = 0; j < 4; ++j) acc[i][j] = (f32x4){0.f, 0.f, 0.f, 0.f};

  auto stage = [&](int slot, int kn) {
    bf16_t* d = lds + slot * 12288;
    gl_lds16(A  + (size_t)(tm + srow) * K + kn + scol,       d + sdst);
    gl_lds16(A  + (size_t)(tm + 128 + srow) * K + kn + scol, d + 4096 + sdst);
    gl_lds16(Bt + (size_t)(tn + srow) * K + kn + scol,       d + 8192 + sdst);
  };

  stage(0, 0);
  stage(1, 32);
  asm volatile("s_waitcnt vmcnt(3)" ::: "memory");
  BAR();

  for (int kt = 0; kt < NT; ++kt) {
    const int slot = kt % 3;
    const bf16_t* aH = lds + slot * 12288 + wm * 32;
    const bf16_t* bH = lds + slot * 12288 + 8192 + wn * 32;

    if (kt + 2 < NT) stage((kt + 2) % 3, (kt + 2) << 5);

    bf16x8 af[4], bf_[4];
#pragma unroll
    for (int q = 0; q < 4; ++q) {
      af[q]  = *(const bf16x8*)(aH + (q * 16 + fr) * 32 + kg * 8);
      bf_[q] = *(const bf16x8*)(bH + (q * 16 + fr) * 32 + kg * 8);
    }
    __builtin_amdgcn_s_setprio(1);
#pragma unroll
    for (int mi = 0; mi < 4; ++mi)
#pragma unroll
      for (int nj = 0; nj < 4; ++nj)
        acc[mi][nj] = __builtin_amdgcn_mfma_f32_16x16x32_bf16(af[mi], bf_[nj], acc[mi][nj], 0, 0, 0);
    __builtin_amdgcn_s_setprio(0);

    if (kt + 2 < NT) {
      asm volatile("s_waitcnt vmcnt(3)" ::: "memory");
    } else if (kt + 1 < NT) {
      asm volatile("s_waitcnt vmcnt(0)" ::: "memory");
    }
    BAR();
  }

  // -------- epilogue: stash -> coalesced ze + fused VQ (register-light) -----
  bf16_t* seb = lds;                                      // [2048] bf16
  float*  shv = (float*)(lds + 2048);                     // [128]  f32 @4096
  float*  wF  = (float*)((char*)lds + 4608 + w * 9216);   // [32][72] f32

  for (int i = t; i < 2048; i += 512) seb[i] = (bf16_t)emb[i];
  if (t < 128) {
    const float* ep = emb + t * 16;
    float s = 0.f;
#pragma unroll
    for (int j = 0; j < 16; ++j) s += ep[j] * ep[j];
    shv[t] = 0.5f * s;
  }
  __syncthreads();

  const int col = fr;
  const int ks8 = kg * 8;
  const bool kact = (ks8 < 16);

#pragma unroll
  for (int h = 0; h < 2; ++h) {
    // stash wave slice (bias added) to wave-private LDS
#pragma unroll
    for (int mi2 = 0; mi2 < 2; ++mi2) {
      const int mi = h * 2 + mi2;
      const int rl0 = mi2 * 16 + kg * 4;
#pragma unroll
      for (int nj = 0; nj < 4; ++nj) {
        const int cl = nj * 16 + fr;
        const float bv = bias[tn + wn + cl];
#pragma unroll
        for (int r = 0; r < 4; ++r)
          wF[(rl0 + r) * 72 + cl] = acc[mi][nj][r] + bv;
      }
    }
    asm volatile("s_waitcnt lgkmcnt(0)" ::: "memory");

    // coalesced ze store from the stash
#pragma unroll
    for (int j = 0; j < 8; ++j) {
      const int rl = j * 4 + (l >> 4);
      const int cl = (l & 15) * 4;
      float4 v = *(const float4*)(wF + rl * 72 + cl);
      *(float4*)(ze + (size_t)(tm + wm + h * 32 + rl) * 2048 + tn + wn + cl) = v;
    }

    for (int ti = 0; ti < 8; ++ti) {
      bf16x8 afrag;
#pragma unroll
      for (int j = 0; j < 8; ++j) afrag[j] = (bf16_t)0.f;
      if (kact) {
        const float* ap = wF + (ti * 4 + (col >> 2)) * 72 + (col & 3) * 16 + ks8;
        float4 a0 = *(const float4*)ap;
        float4 a1 = *(const float4*)(ap + 4);
        afrag[0] = (bf16_t)(-a0.x); afrag[1] = (bf16_t)(-a0.y);
        afrag[2] = (bf16_t)(-a0.z); afrag[3] = (bf16_t)(-a0.w);
        afrag[4] = (bf16_t)(-a1.x); afrag[5] = (bf16_t)(-a1.y);
        afrag[6] = (bf16_t)(-a1.z); afrag[7] = (bf16_t)(-a1.w);
      }

      float bd[4] = {1e30f, 1e30f, 1e30f, 1e30f};
      int   bi[4] = {0, 0, 0, 0};
#pragma unroll
      for (int cb = 0; cb < 8; ++cb) {
        bf16x8 bf;
#pragma unroll
        for (int j = 0; j < 8; ++j) bf[j] = (bf16_t)0.f;
        if (kact) bf = *(const bf16x8*)(seb + (cb * 16 + col) * 16 + ks8);
        const float hvv = shv[cb * 16 + col];
        f32x4 c = (f32x4){hvv, hvv, hvv, hvv};
        f32x4 dd = __builtin_amdgcn_mfma_f32_16x16x32_bf16(afrag, bf, c, 0, 0, 0);
        const int ci = cb * 16 + col;
#pragma unroll
        for (int r2 = 0; r2 < 4; ++r2)
          if (dd[r2] < bd[r2]) { bd[r2] = dd[r2]; bi[r2] = ci; }
      }

#pragma unroll
      for (int r2 = 0; r2 < 4; ++r2) {
        float bdv = bd[r2]; int biv = bi[r2];
#pragma unroll
        for (int m = 1; m < 16; m <<= 1) {
          float od = __shfl_xor(bdv, m);
          int   oi = __shfl_xor(biv, m);
          if (od < bdv || (od == bdv && oi < biv)) { bdv = od; biv = oi; }
        }
        if (col == r2) {
          const int pair = kg * 4 + r2;
          const size_t rg = (size_t)(tm + wm + h * 32 + ti * 4 + (pair >> 2));
          const size_t off = rg * 2048 + (tn + wn + (pair & 3) * 16);
          const bf16_t* eb = seb + biv * 16;
#pragma unroll
          for (int v4 = 0; v4 < 4; ++v4) {
            float4 f;
            f.x = (float)eb[v4 * 4 + 0]; f.y = (float)eb[v4 * 4 + 1];
            f.z = (float)eb[v4 * 4 + 2]; f.w = (float)eb[v4 * 4 + 3];
            *(float4*)(zq + off + v4 * 4) = f;
          }
          *(bf16x8*)(zqb + off)     = ((const bf16x8*)eb)[0];
          *(bf16x8*)(zqb + off + 8) = ((const bf16x8*)eb)[1];
        }
      }
    }
    asm volatile("s_waitcnt lgkmcnt(0)" ::: "memory");
  }
}

// ---------------------------------------------------------------------------
extern "C" void kernel_launch(void* const* d_in, const int* in_sizes, int n_in,
                              void* d_out, int out_size, void* d_ws, size_t ws_size,
                              hipStream_t stream)
{
  const float* y   = (const float*)d_in[0];
  const float* emb = (const float*)d_in[1];
  const float* eW1 = (const float*)d_in[2];
  const float* eb1 = (const float*)d_in[3];
  const float* eW2 = (const float*)d_in[4];
  const float* eb2 = (const float*)d_in[5];
  const float* eW3 = (const float*)d_in[6];
  const float* eb3 = (const float*)d_in[7];
  const float* dW1 = (const float*)d_in[8];
  const float* db1 = (const float*)d_in[9];
  const float* dW2 = (const float*)d_in[10];
  const float* db2 = (const float*)d_in[11];
  const float* dW3 = (const float*)d_in[12];
  const float* db3 = (const float*)d_in[13];

  float* out = (float*)d_out;               // [12800][2520]
  float* ze  = out + 32256000;              // [12800][2048]
  float* zq  = ze + 26214400;               // [12800][2048]

  uint8_t* ws = (uint8_t*)d_ws;
  size_t off = 0;
  auto alloc = [&](size_t bytes) -> void* {
    void* p = ws + off; off += (bytes + 255) & ~(size_t)255; return p;
  };
  bf16_t* X0  = (bf16_t*)alloc(12800ULL * 2560 * 2);
  bf16_t* W1t = (bf16_t*)alloc(1024ULL * 2560 * 2);
  bf16_t* W2t = (bf16_t*)alloc(1024ULL * 1024 * 2);
  bf16_t* W3t = (bf16_t*)alloc(2048ULL * 1024 * 2);
  bf16_t* V1t = (bf16_t*)alloc(1024ULL * 2048 * 2);
  bf16_t* V2t = (bf16_t*)alloc(1024ULL * 1024 * 2);
  bf16_t* V3t = (bf16_t*)alloc(2560ULL * 1024 * 2);
  bf16_t* H1  = (bf16_t*)alloc(12800ULL * 1024 * 2);
  bf16_t* H2  = (bf16_t*)alloc(12800ULL * 1024 * 2);
  bf16_t* ZQb = (bf16_t*)alloc(12800ULL * 2048 * 2);

  prep_kernel<<<27264, 256, 0, stream>>>(y, X0, eW1, W1t, eW2, W2t, eW3, W3t,
                                         dW1, V1t, dW2, V2t, dW3, V3t);

  // encoder
  gemm128<1><<<dim3(8, 50), 512, 0, stream>>>(X0, W1t, eb1, H1, nullptr, 12800, 1024, 2560, 1024);
  gemm128<1><<<dim3(8, 50), 512, 0, stream>>>(H1, W2t, eb2, H2, nullptr, 12800, 1024, 1024, 1024);
  // GEMM3 + fused VQ
  gemm_vq<<<dim3(16, 50), 512, 0, stream>>>(H2, W3t, eb3, emb, ze, zq, ZQb, 12800, 1024);
  // decoder
  gemm128<1><<<dim3(8, 50), 512, 0, stream>>>(ZQb, V1t, db1, H1, nullptr, 12800, 1024, 2048, 1024);
  gemm128<1><<<dim3(8, 50), 512, 0, stream>>>(H1, V2t, db2, H2, nullptr, 12800, 1024, 1024, 1024);
  gemm128<0><<<dim3(20, 50), 512, 0, stream>>>(H2, V3t, db3, nullptr, out, 12800, 2560, 1024, 2520);
}